// Round 10
// baseline (153.088 us; speedup 1.0000x reference)
//
#include <hip/hip_runtime.h>

#define NSTEP 64
#define HDIM 1024
#define BDIM 2048
#define OHH 511

typedef float v2f __attribute__((ext_vector_type(2)));

__device__ __forceinline__ v2f vsplat(float s) { v2f r; r.x = s; r.y = s; return r; }

// global -> LDS async copy, 16 B per lane
#define GLD_LDS16(g, l)                                                        \
    __builtin_amdgcn_global_load_lds(                                          \
        (const __attribute__((address_space(1))) unsigned int*)(g),            \
        (__attribute__((address_space(3))) unsigned int*)(l), 16, 0, 0)

// ---------------------------------------------------------------------------
// Kernel 1: precompute transposed coefficient tables.
//   etab[s][k][lane] (float4 c,sn,sp,cp): even pair p = 8*lane+k, cols 2p,2p+1
//   otab same for odd pair j = 8*lane+k (cols 2j+1,2j+2); j==511 -> identity
//   wtab[q][lane] float4 = (cw0,sw0,cw1,sw1) for cols (16*lane+2q, +2q+1)
// ---------------------------------------------------------------------------
__global__ void coeff_kernel(const float* __restrict__ omega,
                             const float* __restrict__ ETh,
                             const float* __restrict__ OTh,
                             const float* __restrict__ EPh,
                             const float* __restrict__ OPh,
                             float4* __restrict__ etab,
                             float4* __restrict__ otab,
                             float2* __restrict__ wtab)
{
    int idx = blockIdx.x * 256 + threadIdx.x;
    if (idx < NSTEP * 512) {
        int p = idx & 511;
        float c, s, cp, sp;
        __sincosf(ETh[idx], &s, &c);
        __sincosf(EPh[idx], &sp, &cp);
        etab[(idx & ~511) | ((p & 7) << 6) | (p >> 3)] = make_float4(c, s, sp, cp);
    } else if (idx < 2 * NSTEP * 512) {
        int i2 = idx - NSTEP * 512;
        int l = i2 >> 9;
        int j = i2 & 511;
        float4 v;
        if (j < OHH) {
            float c, s, cp, sp;
            __sincosf(OTh[l * OHH + j], &s, &c);
            __sincosf(OPh[l * OHH + j], &sp, &cp);
            v = make_float4(c, s, sp, cp);
        } else {
            v = make_float4(1.f, 0.f, 1.f, 0.f);  // identity rotation
        }
        otab[(i2 & ~511) | ((j & 7) << 6) | (j >> 3)] = v;
    } else if (idx < 2 * NSTEP * 512 + HDIM) {
        int c = idx - 2 * NSTEP * 512;
        float cw, sw;
        __sincosf(omega[c], &sw, &cw);
        int p = c >> 1;
        wtab[(((p & 7) << 6) | (p >> 3)) * 2 + (c & 1)] = make_float2(cw, sw);
    }
}

// Packed complex pair rotation: state A,B are (re,im) v2f; f = (c,sn,sp,cp).
//   t = c*A - sn*B;  B' = c*B + sn*A;  A' = (sp + i*cp) * t
__device__ __forceinline__ void pair_rot(const float4 f, v2f& A, v2f& B) {
    v2f C = vsplat(f.x), S = vsplat(f.y);
    v2f t = C * A - S * B;
    B = C * B + S * A;
    v2f cps; cps.x = -f.w; cps.y = f.w;
    A = vsplat(f.z) * t + cps * t.yx;
}
// Right-boundary variant: update A only, Bn is neighbor's value.
__device__ __forceinline__ void pair_rot_a(const float4 f, v2f& A, const v2f Bn) {
    v2f t = vsplat(f.x) * A - vsplat(f.y) * Bn;
    v2f cps; cps.x = -f.w; cps.y = f.w;
    A = vsplat(f.z) * t + cps * t.yx;
}

// ---------------------------------------------------------------------------
// Kernel 2: R7 structure (wave = 2 rows, 4 waves/block, 256 blocks = 1/CU,
// packed v2f math) + LDS-staged coefficients. R7's wall was per-CU vector-
// memory port time: each wave redundantly loaded the same 17 KB/step slice
// (68 KB/CU/step, all fresh lines -> L2). Now the block stages 16 KB/step
// ONCE via global_load_lds into a double buffer a full step ahead (zero VGPR
// cost), and waves ds_read_b128 their fragments (conflict-free, 128 B/cyc
// shared port). One __syncthreads per step; its vmcnt drain is free because
// the fills are ~900 cycles old.
// ---------------------------------------------------------------------------
__global__ __launch_bounds__(256) void eunn_kernel(
    const float* __restrict__ x_re,
    const float* __restrict__ x_im,
    const float4* __restrict__ etab,
    const float4* __restrict__ otab,
    const float4* __restrict__ wtab,
    float* __restrict__ out)
{
    __shared__ float4 lbuf[2][1024];   // [buf][0..511]=even slice, [512..1023]=odd slice

    const int lane = threadIdx.x & 63;
    const int wave = threadIdx.x >> 6;
    const int row0 = blockIdx.x * 8 + wave * 2;
    const int colbase = lane << 4;
    const int lanem1 = (lane + 63) & 63;   // oc0 slot: k=7 row of lane-1 (lane0 -> identity)
    const int fidx = (wave << 8) + lane;   // this thread's fill slot base (waves 0-1: even, 2-3: odd)

    v2f x[2][16];   // interleaved (re, im) state

    // --- load state (f32 planes), interleave into v2f regs ---
    #pragma unroll
    for (int r = 0; r < 2; ++r) {
        const float4* pr = reinterpret_cast<const float4*>(x_re + (row0 + r) * HDIM + colbase);
        const float4* pi = reinterpret_cast<const float4*>(x_im + (row0 + r) * HDIM + colbase);
        #pragma unroll
        for (int q = 0; q < 4; ++q) {
            float4 vr = pr[q];
            float4 vi = pi[q];
            x[r][4*q+0].x = vr.x; x[r][4*q+0].y = vi.x;
            x[r][4*q+1].x = vr.y; x[r][4*q+1].y = vi.y;
            x[r][4*q+2].x = vr.z; x[r][4*q+2].y = vi.z;
            x[r][4*q+3].x = vr.w; x[r][4*q+3].y = vi.w;
        }
    }

    // --- prologue: stage step-0 coefficient slices into buf 0 ---
    #pragma unroll
    for (int t = 0; t < 4; ++t) {
        int idx = fidx + (t << 6);                       // 0..1023 across the block
        const float4* gsrc = (idx < 512) ? (etab + idx) : (otab + (idx - 512));
        GLD_LDS16(gsrc, &lbuf[0][idx]);
    }
    __syncthreads();   // drains the fills (vmcnt 0 + barrier)

    for (int s = 0; s < NSTEP; ++s) {
        const float4* cur = lbuf[s & 1];

        // issue fills for the NEXT step into the other buffer (async, consumed
        // after the end-of-step barrier -> ~900 cyc of cover, zero registers)
        {
            const int sn = (s + 1 < NSTEP) ? (s + 1) : (NSTEP - 1);
            float4* dst = lbuf[(s + 1) & 1];
            #pragma unroll
            for (int t = 0; t < 4; ++t) {
                int idx = fidx + (t << 6);
                const float4* gsrc = (idx < 512) ? (etab + sn * 512 + idx)
                                                 : (otab + sn * 512 + (idx - 512));
                GLD_LDS16(gsrc, &dst[idx]);
            }
        }

        // coefficient reads for this step (ds_read_b128, conflict-free)
        float4 ec[8], oc[8], oc0;
        #pragma unroll
        for (int k = 0; k < 8; ++k) {
            ec[k] = cur[(k << 6) + lane];
            oc[k] = cur[512 + (k << 6) + lane];
        }
        oc0 = cur[512 + (7 << 6) + lanem1];

        // ---- even layer, boundary pairs first (k=0,7) so shuffles issue early
        pair_rot(ec[0], x[0][0],  x[0][1]);
        pair_rot(ec[0], x[1][0],  x[1][1]);
        pair_rot(ec[7], x[0][14], x[0][15]);
        pair_rot(ec[7], x[1][14], x[1][15]);

        // boundary shuffles on post-even values
        v2f xn[2], xl[2];
        #pragma unroll
        for (int r = 0; r < 2; ++r) {
            xn[r].x = __shfl_down(x[r][0].x, 1, 64);   // right neighbor's col0
            xn[r].y = __shfl_down(x[r][0].y, 1, 64);
            xl[r].x = __shfl_up(x[r][15].x, 1, 64);    // left neighbor's col15
            xl[r].y = __shfl_up(x[r][15].y, 1, 64);
        }

        // remaining even pairs k=1..6
        #pragma unroll
        for (int k = 1; k < 7; ++k) {
            pair_rot(ec[k], x[0][2*k], x[0][2*k+1]);
            pair_rot(ec[k], x[1][2*k], x[1][2*k+1]);
        }

        // ---- odd layer: internal pairs oc[k-1] -> local cols (2k-1, 2k)
        #pragma unroll
        for (int k = 1; k < 8; ++k) {
            pair_rot(oc[k-1], x[0][2*k-1], x[0][2*k]);
            pair_rot(oc[k-1], x[1][2*k-1], x[1][2*k]);
        }
        // right boundary (our col15 = "a", neighbor col0 = "b"): update col15
        pair_rot_a(oc[7], x[0][15], xn[0]);
        pair_rot_a(oc[7], x[1][15], xn[1]);
        // left boundary (left col15 = "a", our col0 = "b"): update col0
        {
            v2f C = vsplat(oc0.x), S = vsplat(oc0.y);
            x[0][0] = C * x[0][0] + S * xl[0];
            x[1][0] = C * x[1][0] + S * xl[1];
        }

        // close the pipeline stage: next-step fills complete + all waves done
        __syncthreads();
    }

    // --- omega phase + de-interleave + store (coalesced) ---
    float4 wc[8];
    #pragma unroll
    for (int q = 0; q < 8; ++q) wc[q] = wtab[(q << 6) + lane];  // (cw0,sw0,cw1,sw1) cols 2q,2q+1

    #pragma unroll
    for (int r = 0; r < 2; ++r) {
        float4* pre = reinterpret_cast<float4*>(out + (row0 + r) * HDIM + colbase);
        float4* pim = reinterpret_cast<float4*>(out + BDIM * HDIM + (row0 + r) * HDIM + colbase);
        #pragma unroll
        for (int h = 0; h < 4; ++h) {
            float4 wa = wc[2*h];      // cols 4h, 4h+1
            float4 wb = wc[2*h + 1];  // cols 4h+2, 4h+3
            v2f X0 = x[r][4*h+0], X1 = x[r][4*h+1], X2 = x[r][4*h+2], X3 = x[r][4*h+3];
            float4 vr, vi;
            vr.x = X0.x * wa.x - X0.y * wa.y;  vi.x = X0.x * wa.y + X0.y * wa.x;
            vr.y = X1.x * wa.z - X1.y * wa.w;  vi.y = X1.x * wa.w + X1.y * wa.z;
            vr.z = X2.x * wb.x - X2.y * wb.y;  vi.z = X2.x * wb.y + X2.y * wb.x;
            vr.w = X3.x * wb.z - X3.y * wb.w;  vi.w = X3.x * wb.w + X3.y * wb.z;
            pre[h] = vr;
            pim[h] = vi;
        }
    }
}

extern "C" void kernel_launch(void* const* d_in, const int* in_sizes, int n_in,
                              void* d_out, int out_size, void* d_ws, size_t ws_size,
                              hipStream_t stream)
{
    const float* x_re  = (const float*)d_in[0];
    const float* x_im  = (const float*)d_in[1];
    const float* omega = (const float*)d_in[2];
    const float* eth   = (const float*)d_in[3];
    const float* oth   = (const float*)d_in[4];
    const float* eph   = (const float*)d_in[5];
    const float* oph   = (const float*)d_in[6];

    char* ws = (char*)d_ws;
    float4* etab = (float4*)ws;                             // 512 KB
    float4* otab = (float4*)(ws + NSTEP * 512 * 16);        // 512 KB
    float2* wtab = (float2*)(ws + 2 * NSTEP * 512 * 16);    // 8 KB

    coeff_kernel<<<260, 256, 0, stream>>>(omega, eth, oth, eph, oph, etab, otab, wtab);
    eunn_kernel<<<BDIM / 8, 256, 0, stream>>>(x_re, x_im, etab, otab,
                                              (const float4*)wtab, (float*)d_out);
}

// Round 11
// 138.718 us; speedup vs baseline: 1.1036x; 1.1036x over previous
//
#include <hip/hip_runtime.h>

#define NSTEP 64
#define HDIM 1024
#define BDIM 2048
#define OHH 511

typedef float v2f __attribute__((ext_vector_type(2)));

__device__ __forceinline__ v2f vsplat(float s) { v2f r; r.x = s; r.y = s; return r; }

// ---------------------------------------------------------------------------
// Kernel 1: repack raw ANGLES into transposed tables (no sincos here — the
// eunn kernel computes sincos in-register, halving its coefficient bytes:
// R7's wall was ~68 KB/step/CU of L1 return-port time for (c,s,sp,cp) loads).
//   aetab[s*256 + k*64 + lane] = (th(p),phi(p),th(p+1),phi(p+1)), p=8*lane+2k
//   aotab same for odd pairs j=8*lane+2k; j==511 pad = (0, pi/2) -> identity
//   wtab[q][lane] float2 pairs, layout proven since R4
// ---------------------------------------------------------------------------
__global__ void repack_kernel(const float* __restrict__ omega,
                              const float* __restrict__ ETh,
                              const float* __restrict__ OTh,
                              const float* __restrict__ EPh,
                              const float* __restrict__ OPh,
                              float4* __restrict__ aetab,
                              float4* __restrict__ aotab,
                              float2* __restrict__ wtab)
{
    int idx = blockIdx.x * 256 + threadIdx.x;
    if (idx < NSTEP * 256) {
        int s = idx >> 8, r = idx & 255, k = r >> 6, lane = r & 63;
        int p = s * 512 + 8 * lane + 2 * k;
        aetab[idx] = make_float4(ETh[p], EPh[p], ETh[p + 1], EPh[p + 1]);
    } else if (idx < 2 * NSTEP * 256) {
        int i = idx - NSTEP * 256;
        int s = i >> 8, r = i & 255, k = r >> 6, lane = r & 63;
        int j0 = 8 * lane + 2 * k;
        float t0 = OTh[s * OHH + j0], f0 = OPh[s * OHH + j0];
        float t1, f1;
        if (j0 + 1 < OHH) {
            t1 = OTh[s * OHH + j0 + 1];
            f1 = OPh[s * OHH + j0 + 1];
        } else {
            t1 = 0.0f;              // c=1, s=0
            f1 = 1.5707963268f;     // sp=1, cp=0  -> identity rotation
        }
        aotab[i] = make_float4(t0, f0, t1, f1);
    } else if (idx < 2 * NSTEP * 256 + HDIM) {
        int c = idx - 2 * NSTEP * 256;
        float cw, sw;
        __sincosf(omega[c], &sw, &cw);
        int p = c >> 1;
        wtab[(((p & 7) << 6) | (p >> 3)) * 2 + (c & 1)] = make_float2(cw, sw);
    }
}

// Packed complex pair rotation: state A,B are (re,im) v2f; f = (c,sn,sp,cp).
//   t = c*A - sn*B;  B' = c*B + sn*A;  A' = (sp + i*cp) * t
__device__ __forceinline__ void pair_rot(const float4 f, v2f& A, v2f& B) {
    v2f C = vsplat(f.x), S = vsplat(f.y);
    v2f t = C * A - S * B;
    B = C * B + S * A;
    v2f cps; cps.x = -f.w; cps.y = f.w;
    A = vsplat(f.z) * t + cps * t.yx;
}
// Right-boundary variant: update A only, Bn is neighbor's value.
__device__ __forceinline__ void pair_rot_a(const float4 f, v2f& A, const v2f Bn) {
    v2f t = vsplat(f.x) * A - vsplat(f.y) * Bn;
    v2f cps; cps.x = -f.w; cps.y = f.w;
    A = vsplat(f.z) * t + cps * t.yx;
}

// sincos a float4 of (th0,phi0,th1,phi1) into two (c,sn,sp,cp) coeff float4s
__device__ __forceinline__ void ang2coef(const float4 a, float4& f0, float4& f1) {
    float sn0, cs0, sp0, cp0, sn1, cs1, sp1, cp1;
    __sincosf(a.x, &sn0, &cs0);
    __sincosf(a.y, &sp0, &cp0);
    __sincosf(a.z, &sn1, &cs1);
    __sincosf(a.w, &sp1, &cp1);
    f0 = make_float4(cs0, sn0, sp0, cp0);
    f1 = make_float4(cs1, sn1, sp1, cp1);
}

// ---------------------------------------------------------------------------
// Kernel 2: R7 champion structure (wave = 2 rows, 1024 waves, 1 block/CU,
// packed v2f math, no barriers) with coefficient loads HALVED: load raw
// angles (8 B/pair) and compute sincos in-register. Even angles prefetched
// one step ahead (R7's proven slot); odd angles loaded at step top, consumed
// mid-step; oc0's (c,s) derived from lane-1's oc[7] via 2 shuffles.
// ---------------------------------------------------------------------------
__global__ __launch_bounds__(256) void eunn_kernel(
    const float* __restrict__ x_re,
    const float* __restrict__ x_im,
    const float4* __restrict__ aetab,
    const float4* __restrict__ aotab,
    const float4* __restrict__ wtab,
    float* __restrict__ out)
{
    const int lane = threadIdx.x & 63;
    const int wave = threadIdx.x >> 6;
    const int row0 = blockIdx.x * 8 + wave * 2;
    const int colbase = lane << 4;

    v2f x[2][16];   // interleaved (re, im) state

    // --- load state (f32 planes), interleave into v2f regs ---
    #pragma unroll
    for (int r = 0; r < 2; ++r) {
        const float4* pr = reinterpret_cast<const float4*>(x_re + (row0 + r) * HDIM + colbase);
        const float4* pi = reinterpret_cast<const float4*>(x_im + (row0 + r) * HDIM + colbase);
        #pragma unroll
        for (int q = 0; q < 4; ++q) {
            float4 vr = pr[q];
            float4 vi = pi[q];
            x[r][4*q+0].x = vr.x; x[r][4*q+0].y = vi.x;
            x[r][4*q+1].x = vr.y; x[r][4*q+1].y = vi.y;
            x[r][4*q+2].x = vr.z; x[r][4*q+2].y = vi.z;
            x[r][4*q+3].x = vr.w; x[r][4*q+3].y = vi.w;
        }
    }

    // --- prologue: load step-0 even angles (coalesced, lane-stride 16 B) ---
    float4 ae[4];
    {
        const float4* p = aetab + lane;
        #pragma unroll
        for (int k = 0; k < 4; ++k) ae[k] = p[k << 6];
    }

    for (int s = 0; s < NSTEP; ++s) {
        // even coefficients from prefetched angles (pure VALU, no mem wait)
        float4 ec[8];
        #pragma unroll
        for (int k = 0; k < 4; ++k) ang2coef(ae[k], ec[2*k], ec[2*k+1]);

        // odd angles for this step (consumed mid-step, ~300 cyc of cover)
        float4 ao[4];
        {
            const float4* p = aotab + s * 256 + lane;
            #pragma unroll
            for (int k = 0; k < 4; ++k) ao[k] = p[k << 6];
        }

        // ---- even layer, boundary pairs first (k=0,7) so shuffles issue early
        pair_rot(ec[0], x[0][0],  x[0][1]);
        pair_rot(ec[0], x[1][0],  x[1][1]);
        pair_rot(ec[7], x[0][14], x[0][15]);
        pair_rot(ec[7], x[1][14], x[1][15]);

        // boundary shuffles on post-even values
        v2f xn[2], xl[2];
        #pragma unroll
        for (int r = 0; r < 2; ++r) {
            xn[r].x = __shfl_down(x[r][0].x, 1, 64);   // right neighbor's col0
            xn[r].y = __shfl_down(x[r][0].y, 1, 64);
            xl[r].x = __shfl_up(x[r][15].x, 1, 64);    // left neighbor's col15
            xl[r].y = __shfl_up(x[r][15].y, 1, 64);
        }

        // remaining even pairs k=1..6
        #pragma unroll
        for (int k = 1; k < 7; ++k) {
            pair_rot(ec[k], x[0][2*k], x[0][2*k+1]);
            pair_rot(ec[k], x[1][2*k], x[1][2*k+1]);
        }

        // prefetch next step's even angles (consumed next iteration)
        {
            const int s2 = (s + 1 < NSTEP) ? (s + 1) : (NSTEP - 1);
            const float4* p = aetab + s2 * 256 + lane;
            #pragma unroll
            for (int k = 0; k < 4; ++k) ae[k] = p[k << 6];
        }

        // odd coefficients from this step's angles
        float4 oc[8];
        #pragma unroll
        for (int k = 0; k < 4; ++k) ang2coef(ao[k], oc[2*k], oc[2*k+1]);

        // left-boundary (c,s) = lane-1's oc[7]; lane 0 -> identity
        float oc0c = __shfl_up(oc[7].x, 1, 64);
        float oc0s = __shfl_up(oc[7].y, 1, 64);
        oc0c = (lane == 0) ? 1.0f : oc0c;
        oc0s = (lane == 0) ? 0.0f : oc0s;

        // ---- odd layer: internal pairs oc[k-1] -> local cols (2k-1, 2k)
        #pragma unroll
        for (int k = 1; k < 8; ++k) {
            pair_rot(oc[k-1], x[0][2*k-1], x[0][2*k]);
            pair_rot(oc[k-1], x[1][2*k-1], x[1][2*k]);
        }
        // right boundary (our col15 = "a", neighbor col0 = "b"): update col15
        pair_rot_a(oc[7], x[0][15], xn[0]);
        pair_rot_a(oc[7], x[1][15], xn[1]);
        // left boundary (left col15 = "a", our col0 = "b"): update col0
        {
            v2f C = vsplat(oc0c), S = vsplat(oc0s);
            x[0][0] = C * x[0][0] + S * xl[0];
            x[1][0] = C * x[1][0] + S * xl[1];
        }
    }

    // --- omega phase + de-interleave + store (coalesced) ---
    float4 wc[8];
    #pragma unroll
    for (int q = 0; q < 8; ++q) wc[q] = wtab[(q << 6) + lane];  // (cw0,sw0,cw1,sw1) cols 2q,2q+1

    #pragma unroll
    for (int r = 0; r < 2; ++r) {
        float4* pre = reinterpret_cast<float4*>(out + (row0 + r) * HDIM + colbase);
        float4* pim = reinterpret_cast<float4*>(out + BDIM * HDIM + (row0 + r) * HDIM + colbase);
        #pragma unroll
        for (int h = 0; h < 4; ++h) {
            float4 wa = wc[2*h];      // cols 4h, 4h+1
            float4 wb = wc[2*h + 1];  // cols 4h+2, 4h+3
            v2f X0 = x[r][4*h+0], X1 = x[r][4*h+1], X2 = x[r][4*h+2], X3 = x[r][4*h+3];
            float4 vr, vi;
            vr.x = X0.x * wa.x - X0.y * wa.y;  vi.x = X0.x * wa.y + X0.y * wa.x;
            vr.y = X1.x * wa.z - X1.y * wa.w;  vi.y = X1.x * wa.w + X1.y * wa.z;
            vr.z = X2.x * wb.x - X2.y * wb.y;  vi.z = X2.x * wb.y + X2.y * wb.x;
            vr.w = X3.x * wb.z - X3.y * wb.w;  vi.w = X3.x * wb.w + X3.y * wb.z;
            pre[h] = vr;
            pim[h] = vi;
        }
    }
}

extern "C" void kernel_launch(void* const* d_in, const int* in_sizes, int n_in,
                              void* d_out, int out_size, void* d_ws, size_t ws_size,
                              hipStream_t stream)
{
    const float* x_re  = (const float*)d_in[0];
    const float* x_im  = (const float*)d_in[1];
    const float* omega = (const float*)d_in[2];
    const float* eth   = (const float*)d_in[3];
    const float* oth   = (const float*)d_in[4];
    const float* eph   = (const float*)d_in[5];
    const float* oph   = (const float*)d_in[6];

    char* ws = (char*)d_ws;
    float4* aetab = (float4*)ws;                            // 256 KB
    float4* aotab = (float4*)(ws + NSTEP * 256 * 16);       // 256 KB
    float2* wtab  = (float2*)(ws + 2 * NSTEP * 256 * 16);   // 8 KB

    repack_kernel<<<132, 256, 0, stream>>>(omega, eth, oth, eph, oph,
                                           aetab, aotab, wtab);
    eunn_kernel<<<BDIM / 8, 256, 0, stream>>>(x_re, x_im, aetab, aotab,
                                              (const float4*)wtab, (float*)d_out);
}

// Round 12
// 126.620 us; speedup vs baseline: 1.2090x; 1.0955x over previous
//
#include <hip/hip_runtime.h>

#define NSTEP 64
#define HDIM 1024
#define BDIM 2048
#define OHH 511

typedef float v2f __attribute__((ext_vector_type(2)));

__device__ __forceinline__ v2f vsplat(float s) { v2f r; r.x = s; r.y = s; return r; }

// Wave-level DPP lane shifts (CDNA keeps gfx9 wave_shr1/wave_shl1).
// Single VALU op, no LDS pipe — replaces ds_bpermute-based __shfl (~120 cyc).
// bound_ctrl=false: edge lane keeps old (=own) value; both edge uses are
// multiplied by 0 (identity rotations), so this is exact.
__device__ __forceinline__ float dpp_up1(float v) {   // lane n <- lane n-1
    int i = __builtin_bit_cast(int, v);
    int r = __builtin_amdgcn_update_dpp(i, i, 0x138, 0xF, 0xF, false);  // wave_shr:1
    return __builtin_bit_cast(float, r);
}
__device__ __forceinline__ float dpp_dn1(float v) {   // lane n <- lane n+1
    int i = __builtin_bit_cast(int, v);
    int r = __builtin_amdgcn_update_dpp(i, i, 0x130, 0xF, 0xF, false);  // wave_shl:1
    return __builtin_bit_cast(float, r);
}

// ---------------------------------------------------------------------------
// Kernel 1: precompute transposed coefficient tables (R7 champion layout).
//   etab[s][k][lane] (float4 c,sn,sp,cp): even pair p = 8*lane+k, cols 2p,2p+1
//   otab same for odd pair j = 8*lane+k (cols 2j+1,2j+2); j==511 -> identity
//   wtab[q][lane] float4 = (cw0,sw0,cw1,sw1) for cols (16*lane+2q, +2q+1)
// ---------------------------------------------------------------------------
__global__ void coeff_kernel(const float* __restrict__ omega,
                             const float* __restrict__ ETh,
                             const float* __restrict__ OTh,
                             const float* __restrict__ EPh,
                             const float* __restrict__ OPh,
                             float4* __restrict__ etab,
                             float4* __restrict__ otab,
                             float2* __restrict__ wtab)
{
    int idx = blockIdx.x * 256 + threadIdx.x;
    if (idx < NSTEP * 512) {
        int p = idx & 511;
        float c, s, cp, sp;
        __sincosf(ETh[idx], &s, &c);
        __sincosf(EPh[idx], &sp, &cp);
        etab[(idx & ~511) | ((p & 7) << 6) | (p >> 3)] = make_float4(c, s, sp, cp);
    } else if (idx < 2 * NSTEP * 512) {
        int i2 = idx - NSTEP * 512;
        int l = i2 >> 9;
        int j = i2 & 511;
        float4 v;
        if (j < OHH) {
            float c, s, cp, sp;
            __sincosf(OTh[l * OHH + j], &s, &c);
            __sincosf(OPh[l * OHH + j], &sp, &cp);
            v = make_float4(c, s, sp, cp);
        } else {
            v = make_float4(1.f, 0.f, 1.f, 0.f);  // identity rotation
        }
        otab[(i2 & ~511) | ((j & 7) << 6) | (j >> 3)] = v;
    } else if (idx < 2 * NSTEP * 512 + HDIM) {
        int c = idx - 2 * NSTEP * 512;
        float cw, sw;
        __sincosf(omega[c], &sw, &cw);
        int p = c >> 1;
        wtab[(((p & 7) << 6) | (p >> 3)) * 2 + (c & 1)] = make_float2(cw, sw);
    }
}

// Packed complex pair rotation: state A,B are (re,im) v2f; f = (c,sn,sp,cp).
//   t = c*A - sn*B;  B' = c*B + sn*A;  A' = (sp + i*cp) * t
__device__ __forceinline__ void pair_rot(const float4 f, v2f& A, v2f& B) {
    v2f C = vsplat(f.x), S = vsplat(f.y);
    v2f t = C * A - S * B;
    B = C * B + S * A;
    v2f cps; cps.x = -f.w; cps.y = f.w;
    A = vsplat(f.z) * t + cps * t.yx;
}
// Right-boundary variant: update A only, Bn is neighbor's value.
__device__ __forceinline__ void pair_rot_a(const float4 f, v2f& A, const v2f Bn) {
    v2f t = vsplat(f.x) * A - vsplat(f.y) * Bn;
    v2f cps; cps.x = -f.w; cps.y = f.w;
    A = vsplat(f.z) * t + cps * t.yx;
}

// ---------------------------------------------------------------------------
// Kernel 2: R7 champion structure byte-for-byte (wave = 2 rows, 1024 waves,
// 1 block/CU, transposed coeff tables, ec prefetched one step ahead, packed
// v2f math) with EXACTLY ONE change: the 8 per-step __shfl boundary
// exchanges are replaced by wave-level DPP mov (v_mov_b32 dpp wave_shr/shl),
// removing ~120-cyc ds_bpermute latencies from the per-step residual.
// ---------------------------------------------------------------------------
__global__ __launch_bounds__(256) void eunn_kernel(
    const float* __restrict__ x_re,
    const float* __restrict__ x_im,
    const float4* __restrict__ etab,
    const float4* __restrict__ otab,
    const float4* __restrict__ wtab,
    float* __restrict__ out)
{
    const int lane = threadIdx.x & 63;
    const int wave = threadIdx.x >> 6;
    const int row0 = blockIdx.x * 8 + wave * 2;
    const int colbase = lane << 4;
    const int lanem1 = (lane + 63) & 63;   // oc0 slot: k=7 row of lane-1 (lane0 -> identity)

    v2f x[2][16];   // interleaved (re, im) state

    // --- load state (f32 planes), interleave into v2f regs ---
    #pragma unroll
    for (int r = 0; r < 2; ++r) {
        const float4* pr = reinterpret_cast<const float4*>(x_re + (row0 + r) * HDIM + colbase);
        const float4* pi = reinterpret_cast<const float4*>(x_im + (row0 + r) * HDIM + colbase);
        #pragma unroll
        for (int q = 0; q < 4; ++q) {
            float4 vr = pr[q];
            float4 vi = pi[q];
            x[r][4*q+0].x = vr.x; x[r][4*q+0].y = vi.x;
            x[r][4*q+1].x = vr.y; x[r][4*q+1].y = vi.y;
            x[r][4*q+2].x = vr.z; x[r][4*q+2].y = vi.z;
            x[r][4*q+3].x = vr.w; x[r][4*q+3].y = vi.w;
        }
    }

    // --- preload even coeffs for step 0 (coalesced: lane-stride 16 B) ---
    float4 ec[8];
    {
        const float4* p = etab + lane;
        #pragma unroll
        for (int k = 0; k < 8; ++k) ec[k] = p[k << 6];
    }

    for (int s = 0; s < NSTEP; ++s) {
        // odd coeffs for this step (consumed after even layer)
        const float4* ob = otab + s * 512;
        float4 oc0 = ob[(7 << 6) + lanem1];
        float4 oc[8];
        #pragma unroll
        for (int k = 0; k < 8; ++k) oc[k] = ob[(k << 6) + lane];

        // ---- even layer, boundary pairs first (k=0,7)
        pair_rot(ec[0], x[0][0],  x[0][1]);
        pair_rot(ec[0], x[1][0],  x[1][1]);
        pair_rot(ec[7], x[0][14], x[0][15]);
        pair_rot(ec[7], x[1][14], x[1][15]);

        // boundary exchange on post-even values via DPP (VALU, ~2 cyc each)
        v2f xn[2], xl[2];
        #pragma unroll
        for (int r = 0; r < 2; ++r) {
            xn[r].x = dpp_dn1(x[r][0].x);    // right neighbor's col0
            xn[r].y = dpp_dn1(x[r][0].y);
            xl[r].x = dpp_up1(x[r][15].x);   // left neighbor's col15
            xl[r].y = dpp_up1(x[r][15].y);
        }

        // remaining even pairs k=1..6
        #pragma unroll
        for (int k = 1; k < 7; ++k) {
            pair_rot(ec[k], x[0][2*k], x[0][2*k+1]);
            pair_rot(ec[k], x[1][2*k], x[1][2*k+1]);
        }

        // prefetch next step's even coeffs (consumed next iteration)
        if (s + 1 < NSTEP) {
            const float4* p = etab + (s + 1) * 512 + lane;
            #pragma unroll
            for (int k = 0; k < 8; ++k) ec[k] = p[k << 6];
        }

        // ---- odd layer: internal pairs oc[k-1] -> local cols (2k-1, 2k)
        #pragma unroll
        for (int k = 1; k < 8; ++k) {
            pair_rot(oc[k-1], x[0][2*k-1], x[0][2*k]);
            pair_rot(oc[k-1], x[1][2*k-1], x[1][2*k]);
        }
        // right boundary (our col15 = "a", neighbor col0 = "b"): update col15
        // (lane63: oc[7] is identity pad, sn=0 -> xn value irrelevant)
        pair_rot_a(oc[7], x[0][15], xn[0]);
        pair_rot_a(oc[7], x[1][15], xn[1]);
        // left boundary (left col15 = "a", our col0 = "b"): update col0
        // (lane0: oc0 is identity, sn=0 -> xl value irrelevant)
        {
            v2f C = vsplat(oc0.x), S = vsplat(oc0.y);
            x[0][0] = C * x[0][0] + S * xl[0];
            x[1][0] = C * x[1][0] + S * xl[1];
        }
    }

    // --- omega phase + de-interleave + store (coalesced) ---
    float4 wc[8];
    #pragma unroll
    for (int q = 0; q < 8; ++q) wc[q] = wtab[(q << 6) + lane];  // (cw0,sw0,cw1,sw1) cols 2q,2q+1

    #pragma unroll
    for (int r = 0; r < 2; ++r) {
        float4* pre = reinterpret_cast<float4*>(out + (row0 + r) * HDIM + colbase);
        float4* pim = reinterpret_cast<float4*>(out + BDIM * HDIM + (row0 + r) * HDIM + colbase);
        #pragma unroll
        for (int h = 0; h < 4; ++h) {
            float4 wa = wc[2*h];      // cols 4h, 4h+1
            float4 wb = wc[2*h + 1];  // cols 4h+2, 4h+3
            v2f X0 = x[r][4*h+0], X1 = x[r][4*h+1], X2 = x[r][4*h+2], X3 = x[r][4*h+3];
            float4 vr, vi;
            vr.x = X0.x * wa.x - X0.y * wa.y;  vi.x = X0.x * wa.y + X0.y * wa.x;
            vr.y = X1.x * wa.z - X1.y * wa.w;  vi.y = X1.x * wa.w + X1.y * wa.z;
            vr.z = X2.x * wb.x - X2.y * wb.y;  vi.z = X2.x * wb.y + X2.y * wb.x;
            vr.w = X3.x * wb.z - X3.y * wb.w;  vi.w = X3.x * wb.w + X3.y * wb.z;
            pre[h] = vr;
            pim[h] = vi;
        }
    }
}

extern "C" void kernel_launch(void* const* d_in, const int* in_sizes, int n_in,
                              void* d_out, int out_size, void* d_ws, size_t ws_size,
                              hipStream_t stream)
{
    const float* x_re  = (const float*)d_in[0];
    const float* x_im  = (const float*)d_in[1];
    const float* omega = (const float*)d_in[2];
    const float* eth   = (const float*)d_in[3];
    const float* oth   = (const float*)d_in[4];
    const float* eph   = (const float*)d_in[5];
    const float* oph   = (const float*)d_in[6];

    char* ws = (char*)d_ws;
    float4* etab = (float4*)ws;                             // 512 KB
    float4* otab = (float4*)(ws + NSTEP * 512 * 16);        // 512 KB
    float2* wtab = (float2*)(ws + 2 * NSTEP * 512 * 16);    // 8 KB

    coeff_kernel<<<260, 256, 0, stream>>>(omega, eth, oth, eph, oph, etab, otab, wtab);
    eunn_kernel<<<BDIM / 8, 256, 0, stream>>>(x_re, x_im, etab, otab,
                                              (const float4*)wtab, (float*)d_out);
}

// Round 13
// 123.922 us; speedup vs baseline: 1.2354x; 1.0218x over previous
//
#include <hip/hip_runtime.h>

#define NSTEP 64
#define HDIM 1024
#define BDIM 2048
#define OHH 511

typedef float v2f __attribute__((ext_vector_type(2)));

__device__ __forceinline__ v2f vsplat(float s) { v2f r; r.x = s; r.y = s; return r; }

// Wave-level DPP lane shifts (single VALU op; R12 proved exact + neutral-cost).
// bound_ctrl=false: edge lane keeps own value; both edge uses are multiplied
// by 0 (identity rotations), so this is exact.
__device__ __forceinline__ float dpp_up1(float v) {   // lane n <- lane n-1
    int i = __builtin_bit_cast(int, v);
    int r = __builtin_amdgcn_update_dpp(i, i, 0x138, 0xF, 0xF, false);  // wave_shr:1
    return __builtin_bit_cast(float, r);
}
__device__ __forceinline__ float dpp_dn1(float v) {   // lane n <- lane n+1
    int i = __builtin_bit_cast(int, v);
    int r = __builtin_amdgcn_update_dpp(i, i, 0x130, 0xF, 0xF, false);  // wave_shl:1
    return __builtin_bit_cast(float, r);
}

// ---------------------------------------------------------------------------
// Kernel 1: precompute transposed coefficient tables (champion layout).
//   etab[s][k][lane] (float4 c,sn,sp,cp): even pair p = 8*lane+k, cols 2p,2p+1
//   otab same for odd pair j = 8*lane+k (cols 2j+1,2j+2); j==511 -> identity
//   wtab[q][lane] float4 = (cw0,sw0,cw1,sw1) for cols (16*lane+2q, +2q+1)
// ---------------------------------------------------------------------------
__global__ void coeff_kernel(const float* __restrict__ omega,
                             const float* __restrict__ ETh,
                             const float* __restrict__ OTh,
                             const float* __restrict__ EPh,
                             const float* __restrict__ OPh,
                             float4* __restrict__ etab,
                             float4* __restrict__ otab,
                             float2* __restrict__ wtab)
{
    int idx = blockIdx.x * 256 + threadIdx.x;
    if (idx < NSTEP * 512) {
        int p = idx & 511;
        float c, s, cp, sp;
        __sincosf(ETh[idx], &s, &c);
        __sincosf(EPh[idx], &sp, &cp);
        etab[(idx & ~511) | ((p & 7) << 6) | (p >> 3)] = make_float4(c, s, sp, cp);
    } else if (idx < 2 * NSTEP * 512) {
        int i2 = idx - NSTEP * 512;
        int l = i2 >> 9;
        int j = i2 & 511;
        float4 v;
        if (j < OHH) {
            float c, s, cp, sp;
            __sincosf(OTh[l * OHH + j], &s, &c);
            __sincosf(OPh[l * OHH + j], &sp, &cp);
            v = make_float4(c, s, sp, cp);
        } else {
            v = make_float4(1.f, 0.f, 1.f, 0.f);  // identity rotation
        }
        otab[(i2 & ~511) | ((j & 7) << 6) | (j >> 3)] = v;
    } else if (idx < 2 * NSTEP * 512 + HDIM) {
        int c = idx - 2 * NSTEP * 512;
        float cw, sw;
        __sincosf(omega[c], &sw, &cw);
        int p = c >> 1;
        wtab[(((p & 7) << 6) | (p >> 3)) * 2 + (c & 1)] = make_float2(cw, sw);
    }
}

// Packed complex pair rotation: state A,B are (re,im) v2f; f = (c,sn,sp,cp).
//   t = c*A - sn*B;  B' = c*B + sn*A;  A' = (sp + i*cp) * t
__device__ __forceinline__ void pair_rot(const float4 f, v2f& A, v2f& B) {
    v2f C = vsplat(f.x), S = vsplat(f.y);
    v2f t = C * A - S * B;
    B = C * B + S * A;
    v2f cps; cps.x = -f.w; cps.y = f.w;
    A = vsplat(f.z) * t + cps * t.yx;
}
// Right-boundary variant: update A only, Bn is neighbor's value.
__device__ __forceinline__ void pair_rot_a(const float4 f, v2f& A, const v2f Bn) {
    v2f t = vsplat(f.x) * A - vsplat(f.y) * Bn;
    v2f cps; cps.x = -f.w; cps.y = f.w;
    A = vsplat(f.z) * t + cps * t.yx;
}

// ---------------------------------------------------------------------------
// Kernel 2: R12 champion byte-for-byte (wave = 2 rows, 1024 waves, 1 block/CU,
// transposed coeff tables, ec prefetched one step ahead, packed v2f math,
// DPP boundary exchange) with ONE change: __launch_bounds__(256, 1).
// Rationale: VGPR_Count was 80 although ~142 regs are needed to keep state
// (64) + ec/oc/oc0 (68) simultaneously live — the compiler was recycling a
// few load-result registers, serializing load->use with exposed vmcnt waits
// (the invariant ~1200 cyc/step idle). min-waves=1 permits up to 512 VGPRs
// so all 17 per-step loads can issue into distinct registers at step top
// and drain under the ~190-instruction compute body.
// ---------------------------------------------------------------------------
__global__ __launch_bounds__(256, 1) void eunn_kernel(
    const float* __restrict__ x_re,
    const float* __restrict__ x_im,
    const float4* __restrict__ etab,
    const float4* __restrict__ otab,
    const float4* __restrict__ wtab,
    float* __restrict__ out)
{
    const int lane = threadIdx.x & 63;
    const int wave = threadIdx.x >> 6;
    const int row0 = blockIdx.x * 8 + wave * 2;
    const int colbase = lane << 4;
    const int lanem1 = (lane + 63) & 63;   // oc0 slot: k=7 row of lane-1 (lane0 -> identity)

    v2f x[2][16];   // interleaved (re, im) state

    // --- load state (f32 planes), interleave into v2f regs ---
    #pragma unroll
    for (int r = 0; r < 2; ++r) {
        const float4* pr = reinterpret_cast<const float4*>(x_re + (row0 + r) * HDIM + colbase);
        const float4* pi = reinterpret_cast<const float4*>(x_im + (row0 + r) * HDIM + colbase);
        #pragma unroll
        for (int q = 0; q < 4; ++q) {
            float4 vr = pr[q];
            float4 vi = pi[q];
            x[r][4*q+0].x = vr.x; x[r][4*q+0].y = vi.x;
            x[r][4*q+1].x = vr.y; x[r][4*q+1].y = vi.y;
            x[r][4*q+2].x = vr.z; x[r][4*q+2].y = vi.z;
            x[r][4*q+3].x = vr.w; x[r][4*q+3].y = vi.w;
        }
    }

    // --- preload even coeffs for step 0 (coalesced: lane-stride 16 B) ---
    float4 ec[8];
    {
        const float4* p = etab + lane;
        #pragma unroll
        for (int k = 0; k < 8; ++k) ec[k] = p[k << 6];
    }

    for (int s = 0; s < NSTEP; ++s) {
        // odd coeffs for this step (consumed after even layer)
        const float4* ob = otab + s * 512;
        float4 oc0 = ob[(7 << 6) + lanem1];
        float4 oc[8];
        #pragma unroll
        for (int k = 0; k < 8; ++k) oc[k] = ob[(k << 6) + lane];

        // ---- even layer, boundary pairs first (k=0,7)
        pair_rot(ec[0], x[0][0],  x[0][1]);
        pair_rot(ec[0], x[1][0],  x[1][1]);
        pair_rot(ec[7], x[0][14], x[0][15]);
        pair_rot(ec[7], x[1][14], x[1][15]);

        // boundary exchange on post-even values via DPP (VALU, ~2 cyc each)
        v2f xn[2], xl[2];
        #pragma unroll
        for (int r = 0; r < 2; ++r) {
            xn[r].x = dpp_dn1(x[r][0].x);    // right neighbor's col0
            xn[r].y = dpp_dn1(x[r][0].y);
            xl[r].x = dpp_up1(x[r][15].x);   // left neighbor's col15
            xl[r].y = dpp_up1(x[r][15].y);
        }

        // remaining even pairs k=1..6
        #pragma unroll
        for (int k = 1; k < 7; ++k) {
            pair_rot(ec[k], x[0][2*k], x[0][2*k+1]);
            pair_rot(ec[k], x[1][2*k], x[1][2*k+1]);
        }

        // prefetch next step's even coeffs (consumed next iteration)
        if (s + 1 < NSTEP) {
            const float4* p = etab + (s + 1) * 512 + lane;
            #pragma unroll
            for (int k = 0; k < 8; ++k) ec[k] = p[k << 6];
        }

        // ---- odd layer: internal pairs oc[k-1] -> local cols (2k-1, 2k)
        #pragma unroll
        for (int k = 1; k < 8; ++k) {
            pair_rot(oc[k-1], x[0][2*k-1], x[0][2*k]);
            pair_rot(oc[k-1], x[1][2*k-1], x[1][2*k]);
        }
        // right boundary (our col15 = "a", neighbor col0 = "b"): update col15
        // (lane63: oc[7] is identity pad, sn=0 -> xn value irrelevant)
        pair_rot_a(oc[7], x[0][15], xn[0]);
        pair_rot_a(oc[7], x[1][15], xn[1]);
        // left boundary (left col15 = "a", our col0 = "b"): update col0
        // (lane0: oc0 is identity, sn=0 -> xl value irrelevant)
        {
            v2f C = vsplat(oc0.x), S = vsplat(oc0.y);
            x[0][0] = C * x[0][0] + S * xl[0];
            x[1][0] = C * x[1][0] + S * xl[1];
        }
    }

    // --- omega phase + de-interleave + store (coalesced) ---
    float4 wc[8];
    #pragma unroll
    for (int q = 0; q < 8; ++q) wc[q] = wtab[(q << 6) + lane];  // (cw0,sw0,cw1,sw1) cols 2q,2q+1

    #pragma unroll
    for (int r = 0; r < 2; ++r) {
        float4* pre = reinterpret_cast<float4*>(out + (row0 + r) * HDIM + colbase);
        float4* pim = reinterpret_cast<float4*>(out + BDIM * HDIM + (row0 + r) * HDIM + colbase);
        #pragma unroll
        for (int h = 0; h < 4; ++h) {
            float4 wa = wc[2*h];      // cols 4h, 4h+1
            float4 wb = wc[2*h + 1];  // cols 4h+2, 4h+3
            v2f X0 = x[r][4*h+0], X1 = x[r][4*h+1], X2 = x[r][4*h+2], X3 = x[r][4*h+3];
            float4 vr, vi;
            vr.x = X0.x * wa.x - X0.y * wa.y;  vi.x = X0.x * wa.y + X0.y * wa.x;
            vr.y = X1.x * wa.z - X1.y * wa.w;  vi.y = X1.x * wa.w + X1.y * wa.z;
            vr.z = X2.x * wb.x - X2.y * wb.y;  vi.z = X2.x * wb.y + X2.y * wb.x;
            vr.w = X3.x * wb.z - X3.y * wb.w;  vi.w = X3.x * wb.w + X3.y * wb.z;
            pre[h] = vr;
            pim[h] = vi;
        }
    }
}

extern "C" void kernel_launch(void* const* d_in, const int* in_sizes, int n_in,
                              void* d_out, int out_size, void* d_ws, size_t ws_size,
                              hipStream_t stream)
{
    const float* x_re  = (const float*)d_in[0];
    const float* x_im  = (const float*)d_in[1];
    const float* omega = (const float*)d_in[2];
    const float* eth   = (const float*)d_in[3];
    const float* oth   = (const float*)d_in[4];
    const float* eph   = (const float*)d_in[5];
    const float* oph   = (const float*)d_in[6];

    char* ws = (char*)d_ws;
    float4* etab = (float4*)ws;                             // 512 KB
    float4* otab = (float4*)(ws + NSTEP * 512 * 16);        // 512 KB
    float2* wtab = (float2*)(ws + 2 * NSTEP * 512 * 16);    // 8 KB

    coeff_kernel<<<260, 256, 0, stream>>>(omega, eth, oth, eph, oph, etab, otab, wtab);
    eunn_kernel<<<BDIM / 8, 256, 0, stream>>>(x_re, x_im, etab, otab,
                                              (const float4*)wtab, (float*)d_out);
}